// Round 4
// baseline (61.210 us; speedup 1.0000x reference)
//
#include <hip/hip_runtime.h>
#include <cstdint>
#include <cstddef>

typedef unsigned short u16;
typedef unsigned int u32;
typedef __bf16 bf16x8 __attribute__((ext_vector_type(8)));
typedef float f32x4 __attribute__((ext_vector_type(4)));
typedef float f32x2 __attribute__((ext_vector_type(2)));

#define M_TOT 16384
#define C_TOT 1000        // classes = GEMM N dimension
#define N_PAD 1024        // padded B rows
#define K_TOT 512
#define OUT_STRIDE 2000   // out row stride in floats (1000 classes x 2)
#define BM 128
#define BN 128
#define BK 32
#define KSTEPS (K_TOT / BK)   // 16
#define MTILES (M_TOT / BM)   // 128
#define NTILES (N_PAD / BN)   // 8
#define NWG (MTILES * NTILES) // 1024

// ---------- f32 -> bf16 (RNE) ----------
__device__ __forceinline__ u16 f2bf(float f) {
  u32 u = __float_as_uint(f);
  u = (u + 0x7FFFu + ((u >> 16) & 1u)) >> 16;
  return (u16)u;
}

// x: f32 -> bf16, 8 elems/thread
__global__ __launch_bounds__(256) void cvt_kernel(const float* __restrict__ src,
                                                  u16* __restrict__ dst, int n8) {
  int i = blockIdx.x * blockDim.x + threadIdx.x;
  if (i >= n8) return;
  const float4* s = (const float4*)src;
  float4 a = s[2 * i], b = s[2 * i + 1];
  ushort4 r0, r1;
  r0.x = f2bf(a.x); r0.y = f2bf(a.y); r0.z = f2bf(a.z); r0.w = f2bf(a.w);
  r1.x = f2bf(b.x); r1.y = f2bf(b.y); r1.z = f2bf(b.z); r1.w = f2bf(b.w);
  ushort4* d = (ushort4*)dst;
  d[2 * i] = r0;
  d[2 * i + 1] = r1;
}

// Wdiff[c,:] = bf16(W[c,0,:] - W[c,1,:]), rows >= C_TOT zero-padded; bdiff[c] = b[2c]-b[2c+1]
__global__ __launch_bounds__(256) void wdiff_kernel(const float* __restrict__ W,
                                                    const float* __restrict__ b,
                                                    u16* __restrict__ wd,
                                                    float* __restrict__ bd) {
  const int i = blockIdx.x * blockDim.x + threadIdx.x;  // 65536 threads
  const int c = i >> 6;        // row 0..1023
  const int seg = i & 63;      // 8-elem segment within the 512-wide row
  if (c >= N_PAD) return;
  ushort4 r0 = {0, 0, 0, 0}, r1 = {0, 0, 0, 0};
  if (c < C_TOT) {
    const float4* w0 = (const float4*)(W + (size_t)(2 * c) * K_TOT) + seg * 2;
    const float4* w1 = (const float4*)(W + (size_t)(2 * c + 1) * K_TOT) + seg * 2;
    float4 a0 = w0[0], a1 = w0[1], c0 = w1[0], c1 = w1[1];
    r0.x = f2bf(a0.x - c0.x); r0.y = f2bf(a0.y - c0.y);
    r0.z = f2bf(a0.z - c0.z); r0.w = f2bf(a0.w - c0.w);
    r1.x = f2bf(a1.x - c1.x); r1.y = f2bf(a1.y - c1.y);
    r1.z = f2bf(a1.z - c1.z); r1.w = f2bf(a1.w - c1.w);
    if (seg == 0) bd[c] = b[2 * c] - b[2 * c + 1];
  } else if (seg == 0) {
    bd[c] = 0.0f;
  }
  ushort4* d = (ushort4*)(wd + (size_t)c * K_TOT);
  d[seg * 2] = r0;
  d[seg * 2 + 1] = r1;
}

// ---------- async global -> LDS, 16B per lane ----------
__device__ __forceinline__ void gload_lds(const u16* g, u16* l) {
  __builtin_amdgcn_global_load_lds((const __attribute__((address_space(1))) u32*)g,
                                   (__attribute__((address_space(3))) u32*)l, 16, 0, 0);
}

// ---------- GEMM (M=16384, N=1024pad, K=512) + fused pairwise log_softmax ----------
// A: x_bf16 [M][512]; B: Wdiff_bf16 [1024][512]; d = A.B^T + bdiff
// out[m][2c+0] = min(d,0)-log1p(exp(-|d|)); out[m][2c+1] = out0 - d
// Grid: 1D NWG with XCD-chunked swizzle: XCD i owns m-tiles [i*16,(i+1)*16)
//   -> per-XCD working set = 2MB A-chunk + 1MB B, L2-resident.
__global__ __launch_bounds__(256, 3) void gemm_ls_kernel(const u16* __restrict__ A,
                                                         const u16* __restrict__ B,
                                                         const float* __restrict__ bdiff,
                                                         float* __restrict__ out) {
  __shared__ u16 As[2][BM * BK];  // 8 KB each
  __shared__ u16 Bs[2][BN * BK];

  const int tid = threadIdx.x;
  const int lane = tid & 63;
  const int w = tid >> 6;          // wave 0..3
  const int wm = w >> 1;           // wave row 0..1
  const int wn = w & 1;            // wave col 0..1

  // XCD-chunked swizzle (NWG=1024 divisible by 8 XCDs -> bijective)
  const int bid = blockIdx.x;
  const int wg = (bid & 7) * (NWG / 8) + (bid >> 3);
  const int m0 = (wg >> 3) * BM;   // m-tile: wg/NTILES
  const int n0 = (wg & 7) * BN;    // n-tile: wg%NTILES

  // staging: tile is 128 rows x 64 bytes; 256 threads x 16B x 2 insts
  const int off0 = tid * 16;
  const int off1 = off0 + 4096;
  const int r0 = off0 >> 6, c0e = (off0 & 63) >> 1;
  const int r1 = off1 >> 6, c1e = (off1 & 63) >> 1;

  const u16* gA0 = A + (size_t)(m0 + r0) * K_TOT + c0e;
  const u16* gA1 = A + (size_t)(m0 + r1) * K_TOT + c1e;
  const u16* gB0 = B + (size_t)(n0 + r0) * K_TOT + c0e;  // padded: unguarded
  const u16* gB1 = B + (size_t)(n0 + r1) * K_TOT + c1e;

  u16* lA0[2] = { &As[0][off0 >> 1], &As[1][off0 >> 1] };
  u16* lA1[2] = { &As[0][off1 >> 1], &As[1][off1 >> 1] };
  u16* lB0[2] = { &Bs[0][off0 >> 1], &Bs[1][off0 >> 1] };
  u16* lB1[2] = { &Bs[0][off1 >> 1], &Bs[1][off1 >> 1] };

  f32x4 acc[4][4] = {};

  gload_lds(gA0, lA0[0]);
  gload_lds(gA1, lA1[0]);
  gload_lds(gB0, lB0[0]);
  gload_lds(gB1, lB1[0]);
  __syncthreads();

  const int ar = lane & 15;
  const int kq = (lane >> 4) * 16;

  int cur = 0;
  for (int kt = 0; kt < KSTEPS; ++kt) {
    if (kt < KSTEPS - 1) {
      const int ko = (kt + 1) * BK;
      const int nb = cur ^ 1;
      gload_lds(gA0 + ko, lA0[nb]);
      gload_lds(gA1 + ko, lA1[nb]);
      gload_lds(gB0 + ko, lB0[nb]);
      gload_lds(gB1 + ko, lB1[nb]);
    }

    bf16x8 af[4], bf[4];
#pragma unroll
    for (int mi = 0; mi < 4; ++mi) {
      const int row = wm * 64 + mi * 16 + ar;
      af[mi] = *(const bf16x8*)((const char*)&As[cur][0] + row * 64 + kq);
    }
#pragma unroll
    for (int ni = 0; ni < 4; ++ni) {
      const int row = wn * 64 + ni * 16 + ar;
      bf[ni] = *(const bf16x8*)((const char*)&Bs[cur][0] + row * 64 + kq);
    }
#pragma unroll
    for (int mi = 0; mi < 4; ++mi)
#pragma unroll
      for (int ni = 0; ni < 4; ++ni)
        acc[mi][ni] = __builtin_amdgcn_mfma_f32_16x16x32_bf16(af[mi], bf[ni], acc[mi][ni], 0, 0, 0);

    __syncthreads();
    cur ^= 1;
  }

  // ---- epilogue: d -> (o0, o1) f32x2 nontemporal store ----
  const int rbase = m0 + wm * 64 + (lane >> 4) * 4;
  const bool full = (n0 + BN <= C_TOT);  // only the n0=896 column needs guarding

#pragma unroll
  for (int ni = 0; ni < 4; ++ni) {
    const int n = n0 + wn * 64 + ni * 16 + ar;   // < 1024 always
    if (full || n < C_TOT) {
      const float bd_r = bdiff[n];
#pragma unroll
      for (int mi = 0; mi < 4; ++mi) {
#pragma unroll
        for (int j = 0; j < 4; ++j) {
          const float d = acc[mi][ni][j] + bd_r;
          const float o0 = fminf(d, 0.0f) - __logf(1.0f + __expf(-fabsf(d)));
          const int row = rbase + mi * 16 + j;
          f32x2 v;
          v.x = o0;
          v.y = o0 - d;
          __builtin_nontemporal_store(v, (f32x2*)(out + (size_t)row * OUT_STRIDE + 2 * n));
        }
      }
    }
  }
}

// ---------- naive fp32 fallback (only if ws too small) ----------
__global__ __launch_bounds__(256) void naive_kernel(const float* __restrict__ x,
                                                    const float* __restrict__ W,
                                                    const float* __restrict__ b,
                                                    float* __restrict__ out) {
  __shared__ float xs[K_TOT];
  const int row = blockIdx.x;
  for (int i = threadIdx.x; i < K_TOT; i += 256) xs[i] = x[(size_t)row * K_TOT + i];
  __syncthreads();
  for (int c = threadIdx.x; c < C_TOT; c += 256) {
    const float* w0 = W + (size_t)c * 1024;
    float l0 = b[c * 2], l1 = b[c * 2 + 1];
    for (int k = 0; k < K_TOT; ++k) {
      const float xv = xs[k];
      l0 += xv * w0[k];
      l1 += xv * w0[K_TOT + k];
    }
    const float d = l0 - l1;
    const float t = __logf(1.0f + __expf(-fabsf(d)));
    out[(size_t)row * OUT_STRIDE + c * 2]     = fminf(d, 0.0f) - t;
    out[(size_t)row * OUT_STRIDE + c * 2 + 1] = fminf(-d, 0.0f) - t;
  }
}

extern "C" void kernel_launch(void* const* d_in, const int* in_sizes, int n_in,
                              void* d_out, int out_size, void* d_ws, size_t ws_size,
                              hipStream_t stream) {
  const float* x = (const float*)d_in[0];   // [16384, 512]
  const float* W = (const float*)d_in[1];   // [1000, 2, 512]
  const float* b = (const float*)d_in[2];   // [1000, 2]
  float* out = (float*)d_out;               // [16384, 1000, 2]

  const size_t nx = (size_t)M_TOT * K_TOT;                  // 8388608 elems
  const size_t nwd = (size_t)N_PAD * K_TOT;                 // 524288 elems
  const size_t need = (nx + nwd) * sizeof(u16) + N_PAD * sizeof(float);

  if (ws_size < need) {
    naive_kernel<<<M_TOT, 256, 0, stream>>>(x, W, b, out);
    return;
  }

  u16* xb = (u16*)d_ws;
  u16* wd = xb + nx;
  float* bd = (float*)(wd + nwd);

  cvt_kernel<<<(int)(nx / 8 + 255) / 256, 256, 0, stream>>>(x, xb, (int)(nx / 8));
  wdiff_kernel<<<(N_PAD * 64) / 256, 256, 0, stream>>>(W, b, wd, bd);

  gemm_ls_kernel<<<NWG, 256, 0, stream>>>(xb, wd, bd, out);
}

// Round 5
// 59.288 us; speedup vs baseline: 1.0324x; 1.0324x over previous
//
#include <hip/hip_runtime.h>
#include <cstdint>
#include <cstddef>

typedef unsigned short u16;
typedef unsigned int u32;
typedef __bf16 bf16x8 __attribute__((ext_vector_type(8)));
typedef float f32x4 __attribute__((ext_vector_type(4)));
typedef float f32x2 __attribute__((ext_vector_type(2)));

#define M_TOT 16384
#define C_TOT 1000        // classes = GEMM N dimension
#define N_PAD 1024        // padded B rows
#define K_TOT 512
#define OUT_STRIDE 2000   // out row stride in floats (1000 classes x 2)
#define BM 256
#define BN 256
#define BK 32
#define KSTEPS (K_TOT / BK)   // 16
#define MTILES (M_TOT / BM)   // 64
#define NTILES (N_PAD / BN)   // 4
#define NWG (MTILES * NTILES) // 256

// ---------- f32 -> bf16 (RNE) ----------
__device__ __forceinline__ u16 f2bf(float f) {
  u32 u = __float_as_uint(f);
  u = (u + 0x7FFFu + ((u >> 16) & 1u)) >> 16;
  return (u16)u;
}

// x: f32 -> bf16, 8 elems/thread
__global__ __launch_bounds__(256) void cvt_kernel(const float* __restrict__ src,
                                                  u16* __restrict__ dst, int n8) {
  int i = blockIdx.x * blockDim.x + threadIdx.x;
  if (i >= n8) return;
  const float4* s = (const float4*)src;
  float4 a = s[2 * i], b = s[2 * i + 1];
  ushort4 r0, r1;
  r0.x = f2bf(a.x); r0.y = f2bf(a.y); r0.z = f2bf(a.z); r0.w = f2bf(a.w);
  r1.x = f2bf(b.x); r1.y = f2bf(b.y); r1.z = f2bf(b.z); r1.w = f2bf(b.w);
  ushort4* d = (ushort4*)dst;
  d[2 * i] = r0;
  d[2 * i + 1] = r1;
}

// Wdiff[c,:] = bf16(W[c,0,:] - W[c,1,:]), rows >= C_TOT zero-padded; bdiff[c] = b[2c]-b[2c+1]
__global__ __launch_bounds__(256) void wdiff_kernel(const float* __restrict__ W,
                                                    const float* __restrict__ b,
                                                    u16* __restrict__ wd,
                                                    float* __restrict__ bd) {
  const int i = blockIdx.x * blockDim.x + threadIdx.x;  // 65536 threads
  const int c = i >> 6;        // row 0..1023
  const int seg = i & 63;      // 8-elem segment within the 512-wide row
  if (c >= N_PAD) return;
  ushort4 r0 = {0, 0, 0, 0}, r1 = {0, 0, 0, 0};
  if (c < C_TOT) {
    const float4* w0 = (const float4*)(W + (size_t)(2 * c) * K_TOT) + seg * 2;
    const float4* w1 = (const float4*)(W + (size_t)(2 * c + 1) * K_TOT) + seg * 2;
    float4 a0 = w0[0], a1 = w0[1], c0 = w1[0], c1 = w1[1];
    r0.x = f2bf(a0.x - c0.x); r0.y = f2bf(a0.y - c0.y);
    r0.z = f2bf(a0.z - c0.z); r0.w = f2bf(a0.w - c0.w);
    r1.x = f2bf(a1.x - c1.x); r1.y = f2bf(a1.y - c1.y);
    r1.z = f2bf(a1.z - c1.z); r1.w = f2bf(a1.w - c1.w);
    if (seg == 0) bd[c] = b[2 * c] - b[2 * c + 1];
  } else if (seg == 0) {
    bd[c] = 0.0f;
  }
  ushort4* d = (ushort4*)(wd + (size_t)c * K_TOT);
  d[seg * 2] = r0;
  d[seg * 2 + 1] = r1;
}

// ---------- async global -> LDS, 16B per lane ----------
__device__ __forceinline__ void gload_lds(const u16* g, u16* l) {
  __builtin_amdgcn_global_load_lds((const __attribute__((address_space(1))) u32*)g,
                                   (__attribute__((address_space(3))) u32*)l, 16, 0, 0);
}

// ---------- GEMM (M=16384, N=1024pad, K=512) + fused pairwise log_softmax ----------
// 256x256 tile, 8 waves (2m x 4n, per-wave 128x64), BK=32, dbuf 64KB LDS.
// A: x_bf16 [M][512]; B: Wdiff_bf16 [1024][512]; d = A.B^T + bdiff
// out[m][2c+0] = min(d,0)-log1p(exp(-|d|)); out[m][2c+1] = out0 - d
__global__ __launch_bounds__(512, 2) void gemm_ls_kernel(const u16* __restrict__ A,
                                                         const u16* __restrict__ B,
                                                         const float* __restrict__ bdiff,
                                                         float* __restrict__ out) {
  __shared__ u16 As[2][BM * BK];  // 16 KB each buffer
  __shared__ u16 Bs[2][BN * BK];  // total static LDS = 64 KB

  const int tid = threadIdx.x;
  const int lane = tid & 63;
  const int w = tid >> 6;          // wave 0..7
  const int wm = w >> 2;           // wave row 0..1  (owns 128 A-rows)
  const int wn = w & 3;            // wave col 0..3  (owns 64 B-rows)

  // XCD-chunked swizzle (NWG=256 divisible by 8 -> bijective, chunk=32)
  const int bid = blockIdx.x;
  const int wg = (bid & 7) * (NWG / 8) + (bid >> 3);
  const int m0 = (wg >> 2) * BM;   // wg / NTILES
  const int n0 = (wg & 3) * BN;    // wg % NTILES

  // ---- staging: per K-step A-tile 256x32 (16KB) + B-tile (16KB); 512 thr x 16B x 4 ----
  const int srow = tid >> 2;       // 0..127
  const int sg = tid & 3;          // 16B granule within 64B row-chunk
  const u16* gA0 = A + (size_t)(m0 + srow) * K_TOT + sg * 8;
  const u16* gA1 = A + (size_t)(m0 + 128 + srow) * K_TOT + sg * 8;
  const u16* gB0 = B + (size_t)(n0 + srow) * K_TOT + sg * 8;        // padded: unguarded
  const u16* gB1 = B + (size_t)(n0 + 128 + srow) * K_TOT + sg * 8;

  const int lo0 = tid * 8;         // elem offset, rows 0..127
  const int lo1 = tid * 8 + 4096;  // rows 128..255

  f32x4 acc[8][4] = {};

  // prologue: stage k-tile 0 into buf 0
  gload_lds(gA0, &As[0][lo0]);
  gload_lds(gA1, &As[0][lo1]);
  gload_lds(gB0, &Bs[0][lo0]);
  gload_lds(gB1, &Bs[0][lo1]);
  __syncthreads();

  const int ar = lane & 15;
  const int kq = (lane >> 4) * 16;  // byte offset of this lane's 8-elem k-slice

  int cur = 0;
  for (int kt = 0; kt < KSTEPS; ++kt) {
    if (kt < KSTEPS - 1) {  // issue next-tile loads before compute
      const int ko = (kt + 1) * BK;
      const int nb = cur ^ 1;
      gload_lds(gA0 + ko, &As[nb][lo0]);
      gload_lds(gA1 + ko, &As[nb][lo1]);
      gload_lds(gB0 + ko, &Bs[nb][lo0]);
      gload_lds(gB1 + ko, &Bs[nb][lo1]);
    }

    bf16x8 af[8], bf[4];
#pragma unroll
    for (int mi = 0; mi < 8; ++mi) {
      const int row = wm * 128 + mi * 16 + ar;
      af[mi] = *(const bf16x8*)((const char*)&As[cur][0] + row * 64 + kq);
    }
#pragma unroll
    for (int ni = 0; ni < 4; ++ni) {
      const int row = wn * 64 + ni * 16 + ar;
      bf[ni] = *(const bf16x8*)((const char*)&Bs[cur][0] + row * 64 + kq);
    }
#pragma unroll
    for (int mi = 0; mi < 8; ++mi)
#pragma unroll
      for (int ni = 0; ni < 4; ++ni)
        acc[mi][ni] = __builtin_amdgcn_mfma_f32_16x16x32_bf16(af[mi], bf[ni], acc[mi][ni], 0, 0, 0);

    __syncthreads();
    cur ^= 1;
  }

  // ---- epilogue: d -> (o0, o1) f32x2 store ----
  const int rbase = m0 + wm * 128 + (lane >> 4) * 4;
  const bool full = (n0 + BN <= C_TOT);  // only the n0=768 tile needs guarding

#pragma unroll
  for (int ni = 0; ni < 4; ++ni) {
    const int n = n0 + wn * 64 + ni * 16 + ar;   // < 1024 always
    if (full || n < C_TOT) {
      const float bd_r = bdiff[n];
#pragma unroll
      for (int mi = 0; mi < 8; ++mi) {
#pragma unroll
        for (int j = 0; j < 4; ++j) {
          const float d = acc[mi][ni][j] + bd_r;
          const float o0 = fminf(d, 0.0f) - __logf(1.0f + __expf(-fabsf(d)));
          const int row = rbase + mi * 16 + j;
          f32x2 v;
          v.x = o0;
          v.y = o0 - d;
          *(f32x2*)(out + (size_t)row * OUT_STRIDE + 2 * n) = v;
        }
      }
    }
  }
}

// ---------- naive fp32 fallback (only if ws too small) ----------
__global__ __launch_bounds__(256) void naive_kernel(const float* __restrict__ x,
                                                    const float* __restrict__ W,
                                                    const float* __restrict__ b,
                                                    float* __restrict__ out) {
  __shared__ float xs[K_TOT];
  const int row = blockIdx.x;
  for (int i = threadIdx.x; i < K_TOT; i += 256) xs[i] = x[(size_t)row * K_TOT + i];
  __syncthreads();
  for (int c = threadIdx.x; c < C_TOT; c += 256) {
    const float* w0 = W + (size_t)c * 1024;
    float l0 = b[c * 2], l1 = b[c * 2 + 1];
    for (int k = 0; k < K_TOT; ++k) {
      const float xv = xs[k];
      l0 += xv * w0[k];
      l1 += xv * w0[K_TOT + k];
    }
    const float d = l0 - l1;
    const float t = __logf(1.0f + __expf(-fabsf(d)));
    out[(size_t)row * OUT_STRIDE + c * 2]     = fminf(d, 0.0f) - t;
    out[(size_t)row * OUT_STRIDE + c * 2 + 1] = fminf(-d, 0.0f) - t;
  }
}

extern "C" void kernel_launch(void* const* d_in, const int* in_sizes, int n_in,
                              void* d_out, int out_size, void* d_ws, size_t ws_size,
                              hipStream_t stream) {
  const float* x = (const float*)d_in[0];   // [16384, 512]
  const float* W = (const float*)d_in[1];   // [1000, 2, 512]
  const float* b = (const float*)d_in[2];   // [1000, 2]
  float* out = (float*)d_out;               // [16384, 1000, 2]

  const size_t nx = (size_t)M_TOT * K_TOT;                  // 8388608 elems
  const size_t nwd = (size_t)N_PAD * K_TOT;                 // 524288 elems
  const size_t need = (nx + nwd) * sizeof(u16) + N_PAD * sizeof(float);

  if (ws_size < need) {
    naive_kernel<<<M_TOT, 256, 0, stream>>>(x, W, b, out);
    return;
  }

  u16* xb = (u16*)d_ws;
  u16* wd = xb + nx;
  float* bd = (float*)(wd + nwd);

  cvt_kernel<<<(int)(nx / 8 + 255) / 256, 256, 0, stream>>>(x, xb, (int)(nx / 8));
  wdiff_kernel<<<(N_PAD * 64) / 256, 256, 0, stream>>>(W, b, wd, bd);

  gemm_ls_kernel<<<NWG, 512, 0, stream>>>(xb, wd, bd, out);
}

// Round 6
// 57.880 us; speedup vs baseline: 1.0575x; 1.0243x over previous
//
#include <hip/hip_runtime.h>
#include <cstdint>
#include <cstddef>

typedef unsigned short u16;
typedef unsigned int u32;
typedef __bf16 bf16x8 __attribute__((ext_vector_type(8)));
typedef float f32x4 __attribute__((ext_vector_type(4)));
typedef float f32x2 __attribute__((ext_vector_type(2)));

#define M_TOT 16384
#define C_TOT 1000        // classes = GEMM N dimension
#define N_PAD 1024        // padded B rows
#define K_TOT 512
#define OUT_STRIDE 2000   // out row stride in floats (1000 classes x 2)
#define BM 128            // per-step m-tile
#define BN 256
#define BK 32
#define KSTEPS (K_TOT / BK)   // 16
#define TILES_PER_BLOCK 2     // sequential m-tiles per block (write/compute overlap)
#define NWG 256               // (16384/(128*2)) * (1024/256) = 64*4

// ---------- f32 -> bf16 (RNE) ----------
__device__ __forceinline__ u16 f2bf(float f) {
  u32 u = __float_as_uint(f);
  u = (u + 0x7FFFu + ((u >> 16) & 1u)) >> 16;
  return (u16)u;
}

// Fused prep: blocks [0,4096) convert x f32->bf16 (8 elems/thread);
// blocks [4096,4352) build Wdiff bf16 (zero-padded to 1024 rows) + bdiff.
__global__ __launch_bounds__(256) void prep_kernel(const float* __restrict__ x,
                                                   const float* __restrict__ W,
                                                   const float* __restrict__ b,
                                                   u16* __restrict__ xb,
                                                   u16* __restrict__ wd,
                                                   float* __restrict__ bd) {
  if (blockIdx.x < 4096) {
    const int i = blockIdx.x * 256 + threadIdx.x;   // granule of 8 elems
    const float4* s = (const float4*)x;
    float4 a = s[2 * i], c = s[2 * i + 1];
    ushort4 r0, r1;
    r0.x = f2bf(a.x); r0.y = f2bf(a.y); r0.z = f2bf(a.z); r0.w = f2bf(a.w);
    r1.x = f2bf(c.x); r1.y = f2bf(c.y); r1.z = f2bf(c.z); r1.w = f2bf(c.w);
    ushort4* d = (ushort4*)xb;
    d[2 * i] = r0;
    d[2 * i + 1] = r1;
  } else {
    const int i = (blockIdx.x - 4096) * 256 + threadIdx.x;  // 65536 threads
    const int c = i >> 6;        // row 0..1023
    const int seg = i & 63;      // 8-elem segment of the 512-wide row
    ushort4 r0 = {0, 0, 0, 0}, r1 = {0, 0, 0, 0};
    if (c < C_TOT) {
      const float4* w0 = (const float4*)(W + (size_t)(2 * c) * K_TOT) + seg * 2;
      const float4* w1 = (const float4*)(W + (size_t)(2 * c + 1) * K_TOT) + seg * 2;
      float4 a0 = w0[0], a1 = w0[1], c0 = w1[0], c1 = w1[1];
      r0.x = f2bf(a0.x - c0.x); r0.y = f2bf(a0.y - c0.y);
      r0.z = f2bf(a0.z - c0.z); r0.w = f2bf(a0.w - c0.w);
      r1.x = f2bf(a1.x - c1.x); r1.y = f2bf(a1.y - c1.y);
      r1.z = f2bf(a1.z - c1.z); r1.w = f2bf(a1.w - c1.w);
      if (seg == 0) bd[c] = b[2 * c] - b[2 * c + 1];
    } else if (seg == 0) {
      bd[c] = 0.0f;
    }
    ushort4* d = (ushort4*)(wd + (size_t)c * K_TOT);
    d[seg * 2] = r0;
    d[seg * 2 + 1] = r1;
  }
}

// ---------- async global -> LDS, 16B per lane ----------
__device__ __forceinline__ void gload_lds(const u16* g, u16* l) {
  __builtin_amdgcn_global_load_lds((const __attribute__((address_space(1))) u32*)g,
                                   (__attribute__((address_space(3))) u32*)l, 16, 0, 0);
}

// ---------- GEMM (M=16384, N=1024pad, K=512) + fused pairwise log_softmax ----------
// Per block: 2 sequential 128x256 tiles (same n-panel, consecutive m).
// Tile t+1's prologue loads are issued BEFORE tile t's epilogue, so the
// 256KB/tile output store burst drains to HBM under tile t+1's K-loop.
// 8 waves (2m x 4n), per-wave 64x64, acc[4][4]; dbuf LDS = 48 KB.
__global__ __launch_bounds__(512, 2) void gemm_ls_kernel(const u16* __restrict__ A,
                                                         const u16* __restrict__ B,
                                                         const float* __restrict__ bdiff,
                                                         float* __restrict__ out) {
  __shared__ u16 As[2][BM * BK];  // 8 KB per buffer
  __shared__ u16 Bs[2][BN * BK];  // 16 KB per buffer

  const int tid = threadIdx.x;
  const int lane = tid & 63;
  const int w = tid >> 6;          // wave 0..7
  const int wm = w >> 2;           // 0..1: owns 64 A-rows
  const int wn = w & 3;            // 0..3: owns 64 B-rows

  // XCD-chunked swizzle (NWG=256, chunk 32/XCD, bijective)
  const int bid = blockIdx.x;
  const int wg = (bid & 7) * (NWG / 8) + (bid >> 3);
  const int m_base = (wg >> 2) * (BM * TILES_PER_BLOCK);  // 256-row super-tile
  const int n0 = (wg & 3) * BN;

  // ---- staging addresses: A-tile 128x32 (8KB, 1 inst), B-tile 256x32 (16KB, 2 insts) ----
  const int srow = tid >> 2;       // 0..127
  const int sg = tid & 3;          // 16B granule in 64B row-chunk
  const u16* gA = A + (size_t)(m_base + srow) * K_TOT + sg * 8;
  const u16* gB0 = B + (size_t)(n0 + srow) * K_TOT + sg * 8;        // padded: unguarded
  const u16* gB1 = gB0 + (size_t)128 * K_TOT;

  const int loA = tid * 8;         // elems
  const int loB0 = tid * 8;
  const int loB1 = tid * 8 + 4096;

  const int ar = lane & 15;
  const int kq = (lane >> 4) * 16;  // byte offset of lane's 8-elem k-slice

  // prologue: tile 0, K-step 0 -> buf 0
  gload_lds(gA, &As[0][loA]);
  gload_lds(gB0, &Bs[0][loB0]);
  gload_lds(gB1, &Bs[0][loB1]);

  int cur = 0;
#pragma unroll
  for (int t = 0; t < TILES_PER_BLOCK; ++t) {
    const u16* gAt = gA + (size_t)t * BM * K_TOT;
    f32x4 acc[4][4] = {};

    __syncthreads();  // waits prologue loads (and prior tile's store acks)

    for (int kt = 0; kt < KSTEPS; ++kt) {
      if (kt < KSTEPS - 1) {
        const int ko = (kt + 1) * BK;
        const int nb = cur ^ 1;
        gload_lds(gAt + ko, &As[nb][loA]);
        gload_lds(gB0 + ko, &Bs[nb][loB0]);
        gload_lds(gB1 + ko, &Bs[nb][loB1]);
      }

      bf16x8 af[4], bf[4];
#pragma unroll
      for (int mi = 0; mi < 4; ++mi) {
        const int row = wm * 64 + mi * 16 + ar;
        af[mi] = *(const bf16x8*)((const char*)&As[cur][0] + row * 64 + kq);
      }
#pragma unroll
      for (int ni = 0; ni < 4; ++ni) {
        const int row = wn * 64 + ni * 16 + ar;
        bf[ni] = *(const bf16x8*)((const char*)&Bs[cur][0] + row * 64 + kq);
      }
#pragma unroll
      for (int mi = 0; mi < 4; ++mi)
#pragma unroll
        for (int ni = 0; ni < 4; ++ni)
          acc[mi][ni] = __builtin_amdgcn_mfma_f32_16x16x32_bf16(af[mi], bf[ni], acc[mi][ni], 0, 0, 0);

      __syncthreads();
      cur ^= 1;
    }

    // issue next tile's prologue BEFORE this tile's epilogue: its HBM latency
    // and this tile's store burst both hide under upcoming work
    if (t + 1 < TILES_PER_BLOCK) {
      gload_lds(gAt + BM * K_TOT, &As[cur][loA]);   // buf `cur` is free here
      gload_lds(gB0, &Bs[cur][loB0]);
      gload_lds(gB1, &Bs[cur][loB1]);
    }

    // ---- epilogue tile t: d -> (o0, o1) f32x2 store ----
    const int m0 = m_base + t * BM;
    const int rbase = m0 + wm * 64 + (lane >> 4) * 4;
    const bool full = (n0 + BN <= C_TOT);  // only n0=768 needs guarding

#pragma unroll
    for (int ni = 0; ni < 4; ++ni) {
      const int n = n0 + wn * 64 + ni * 16 + ar;   // < 1024 always
      if (full || n < C_TOT) {
        const float bd_r = bdiff[n];
#pragma unroll
        for (int mi = 0; mi < 4; ++mi) {
#pragma unroll
          for (int j = 0; j < 4; ++j) {
            const float d = acc[mi][ni][j] + bd_r;
            const float o0 = fminf(d, 0.0f) - __logf(1.0f + __expf(-fabsf(d)));
            const int row = rbase + mi * 16 + j;
            f32x2 v;
            v.x = o0;
            v.y = o0 - d;
            *(f32x2*)(out + (size_t)row * OUT_STRIDE + 2 * n) = v;
          }
        }
      }
    }
  }
}

// ---------- naive fp32 fallback (only if ws too small) ----------
__global__ __launch_bounds__(256) void naive_kernel(const float* __restrict__ x,
                                                    const float* __restrict__ W,
                                                    const float* __restrict__ b,
                                                    float* __restrict__ out) {
  __shared__ float xs[K_TOT];
  const int row = blockIdx.x;
  for (int i = threadIdx.x; i < K_TOT; i += 256) xs[i] = x[(size_t)row * K_TOT + i];
  __syncthreads();
  for (int c = threadIdx.x; c < C_TOT; c += 256) {
    const float* w0 = W + (size_t)c * 1024;
    float l0 = b[c * 2], l1 = b[c * 2 + 1];
    for (int k = 0; k < K_TOT; ++k) {
      const float xv = xs[k];
      l0 += xv * w0[k];
      l1 += xv * w0[K_TOT + k];
    }
    const float d = l0 - l1;
    const float t = __logf(1.0f + __expf(-fabsf(d)));
    out[(size_t)row * OUT_STRIDE + c * 2]     = fminf(d, 0.0f) - t;
    out[(size_t)row * OUT_STRIDE + c * 2 + 1] = fminf(-d, 0.0f) - t;
  }
}

extern "C" void kernel_launch(void* const* d_in, const int* in_sizes, int n_in,
                              void* d_out, int out_size, void* d_ws, size_t ws_size,
                              hipStream_t stream) {
  const float* x = (const float*)d_in[0];   // [16384, 512]
  const float* W = (const float*)d_in[1];   // [1000, 2, 512]
  const float* b = (const float*)d_in[2];   // [1000, 2]
  float* out = (float*)d_out;               // [16384, 1000, 2]

  const size_t nx = (size_t)M_TOT * K_TOT;                  // 8388608 elems
  const size_t nwd = (size_t)N_PAD * K_TOT;                 // 524288 elems
  const size_t need = (nx + nwd) * sizeof(u16) + N_PAD * sizeof(float);

  if (ws_size < need) {
    naive_kernel<<<M_TOT, 256, 0, stream>>>(x, W, b, out);
    return;
  }

  u16* xb = (u16*)d_ws;
  u16* wd = xb + nx;
  float* bd = (float*)(wd + nwd);

  prep_kernel<<<4096 + 256, 256, 0, stream>>>(x, W, b, xb, wd, bd);
  gemm_ls_kernel<<<NWG, 512, 0, stream>>>(xb, wd, bd, out);
}

// Round 7
// 52.249 us; speedup vs baseline: 1.1715x; 1.1078x over previous
//
#include <hip/hip_runtime.h>
#include <cstdint>
#include <cstddef>

typedef unsigned short u16;
typedef unsigned int u32;
typedef __bf16 bf16x8 __attribute__((ext_vector_type(8)));
typedef float f32x4 __attribute__((ext_vector_type(4)));
typedef float f32x2 __attribute__((ext_vector_type(2)));

#define M_TOT 16384
#define C_TOT 1000        // classes = GEMM N dimension
#define N_PAD 1024        // padded B rows
#define K_TOT 512
#define OUT_STRIDE 2000   // out row stride in floats
#define BM 128
#define BN 128
#define BK 32
#define NT 16             // K-tiles: 512/32
#define NWG 1024          // (16384/128) * (1024/128)

// ---------- f32 -> bf16 (RNE) ----------
__device__ __forceinline__ u16 f2bf(float f) {
  u32 u = __float_as_uint(f);
  u = (u + 0x7FFFu + ((u >> 16) & 1u)) >> 16;
  return (u16)u;
}

// Fused prep: blocks [0,4096) convert x f32->bf16 (8 elems/thread);
// blocks [4096,4352) build Wdiff bf16 (zero-padded to 1024 rows) + bdiff.
__global__ __launch_bounds__(256) void prep_kernel(const float* __restrict__ x,
                                                   const float* __restrict__ W,
                                                   const float* __restrict__ b,
                                                   u16* __restrict__ xb,
                                                   u16* __restrict__ wd,
                                                   float* __restrict__ bd) {
  if (blockIdx.x < 4096) {
    const int i = blockIdx.x * 256 + threadIdx.x;   // granule of 8 elems
    const float4* s = (const float4*)x;
    float4 a = s[2 * i], c = s[2 * i + 1];
    ushort4 r0, r1;
    r0.x = f2bf(a.x); r0.y = f2bf(a.y); r0.z = f2bf(a.z); r0.w = f2bf(a.w);
    r1.x = f2bf(c.x); r1.y = f2bf(c.y); r1.z = f2bf(c.z); r1.w = f2bf(c.w);
    ushort4* d = (ushort4*)xb;
    d[2 * i] = r0;
    d[2 * i + 1] = r1;
  } else {
    const int i = (blockIdx.x - 4096) * 256 + threadIdx.x;  // 65536 threads
    const int c = i >> 6;        // row 0..1023
    const int seg = i & 63;      // 8-elem segment of the 512-wide row
    ushort4 r0 = {0, 0, 0, 0}, r1 = {0, 0, 0, 0};
    if (c < C_TOT) {
      const float4* w0 = (const float4*)(W + (size_t)(2 * c) * K_TOT) + seg * 2;
      const float4* w1 = (const float4*)(W + (size_t)(2 * c + 1) * K_TOT) + seg * 2;
      float4 a0 = w0[0], a1 = w0[1], c0 = w1[0], c1 = w1[1];
      r0.x = f2bf(a0.x - c0.x); r0.y = f2bf(a0.y - c0.y);
      r0.z = f2bf(a0.z - c0.z); r0.w = f2bf(a0.w - c0.w);
      r1.x = f2bf(a1.x - c1.x); r1.y = f2bf(a1.y - c1.y);
      r1.z = f2bf(a1.z - c1.z); r1.w = f2bf(a1.w - c1.w);
      if (seg == 0) bd[c] = b[2 * c] - b[2 * c + 1];
    } else if (seg == 0) {
      bd[c] = 0.0f;
    }
    ushort4* d = (ushort4*)(wd + (size_t)c * K_TOT);
    d[seg * 2] = r0;
    d[seg * 2 + 1] = r1;
  }
}

// ---------- async global -> LDS, 16B per lane ----------
__device__ __forceinline__ void gload_lds(const u16* g, u16* l) {
  __builtin_amdgcn_global_load_lds((const __attribute__((address_space(1))) u32*)g,
                                   (__attribute__((address_space(3))) u32*)l, 16, 0, 0);
}

// Stage one 8KB operand tile (128 rows x 32 bf16, row-major stride K_TOT) into
// a swizzled LDS buffer. Layout: granule(r,q) [16B units, q=0..3] lives at
//   lrow = r & 63, pos = (((r>>6)<<2) | q) ^ (r & 7), byte = lrow*128 + pos*16.
// LDS dest is linear (lane*16); the global SOURCE is inverse-swizzled (m173).
// Each wave instr reads 16 full 64B cachelines -> HBM-optimal.
__device__ __forceinline__ void stage8k(const u16* __restrict__ gbase,
                                        u16* lb, int tid) {
#pragma unroll
  for (int i = 0; i < 2; ++i) {
    const int g = i * 256 + tid;          // dest granule index 0..511
    const int lrow = g >> 3;
    const int u = (g & 7) ^ (lrow & 7);   // inverse swizzle (XOR involution)
    const int r = lrow | ((u >> 2) << 6);
    const int q = u & 3;
    gload_lds(gbase + (size_t)r * K_TOT + q * 8, lb + (size_t)g * 8);
  }
}

#define VMW(N) asm volatile("s_waitcnt vmcnt(" #N ")" ::: "memory")
#define CFENCE asm volatile("" ::: "memory")

// ---------- GEMM (M=16384, N=1024pad, K=512) + fused pairwise log_softmax ----------
// 128x128 tile, 4 waves (2x2), acc[4][4]; 4 swizzled LDS buffers (64KB),
// depth-3 prefetch with counted vmcnt (8 steady, 4/0 tail), ONE barrier/K-step.
// d = A.B^T + bdiff; out[m][2c] = min(d,0)-log1p(e^-|d|); out[m][2c+1] = out0 - d.
__global__ __launch_bounds__(256, 2) void gemm_ls_kernel(const u16* __restrict__ A,
                                                         const u16* __restrict__ B,
                                                         const float* __restrict__ bdiff,
                                                         float* __restrict__ out) {
  __shared__ u16 As[4][4096];  // 4 buffers x 8KB
  __shared__ u16 Bs[4][4096];  // total 64KB static

  const int tid = threadIdx.x;
  const int lane = tid & 63;
  const int w = tid >> 6;          // wave 0..3
  const int wm = w >> 1;           // 0..1
  const int wn = w & 1;            // 0..1

  // XCD-chunked swizzle (NWG=1024, 128 blocks/XCD, bijective)
  const int bid = blockIdx.x;
  const int wg = (bid & 7) * (NWG / 8) + (bid >> 3);
  const int m0 = (wg >> 3) * BM;
  const int n0 = (wg & 7) * BN;

  const u16* gA = A + (size_t)m0 * K_TOT;
  const u16* gB = B + (size_t)n0 * K_TOT;   // padded rows: unguarded

  // per-lane swizzled LDS byte offsets for the 4 A-frags / 4 B-frags
  const int ar = lane & 15;
  const int kq4 = lane >> 4;       // 16B k-granule index within BK row
  int offA[4], offB[4];
#pragma unroll
  for (int i = 0; i < 4; ++i) {
    int r = wm * 64 + i * 16 + ar;
    offA[i] = (r & 63) * 128 + (((((r >> 6) << 2) | kq4) ^ (r & 7)) << 4);
    r = wn * 64 + i * 16 + ar;
    offB[i] = (r & 63) * 128 + (((((r >> 6) << 2) | kq4) ^ (r & 7)) << 4);
  }

  f32x4 acc[4][4] = {};

#define STAGEAB(t)                                   \
  do {                                               \
    const int _b = (t) & 3;                          \
    stage8k(gA + (t) * BK, &As[_b][0], tid);         \
    stage8k(gB + (t) * BK, &Bs[_b][0], tid);         \
  } while (0)

#define COMPUTE(cb)                                                         \
  do {                                                                      \
    bf16x8 af[4], bf[4];                                                    \
    _Pragma("unroll") for (int i = 0; i < 4; ++i)                           \
        af[i] = *(const bf16x8*)((const char*)&As[(cb)][0] + offA[i]);      \
    _Pragma("unroll") for (int i = 0; i < 4; ++i)                           \
        bf[i] = *(const bf16x8*)((const char*)&Bs[(cb)][0] + offB[i]);      \
    _Pragma("unroll") for (int mi = 0; mi < 4; ++mi)                        \
        _Pragma("unroll") for (int ni = 0; ni < 4; ++ni)                    \
            acc[mi][ni] = __builtin_amdgcn_mfma_f32_16x16x32_bf16(          \
                af[mi], bf[ni], acc[mi][ni], 0, 0, 0);                      \
  } while (0)

  // prologue: 3 tiles in flight (12 loads/wave)
  STAGEAB(0);
  STAGEAB(1);
  STAGEAB(2);

  // steady state: wait-to-8 retires exactly tile t; tiles t+1,t+2 stay in flight
  for (int t = 0; t < 14; ++t) {
    VMW(8);
    __builtin_amdgcn_s_barrier();
    CFENCE;
    if (t < 13) STAGEAB(t + 3);
    COMPUTE(t & 3);
  }
  VMW(4);
  __builtin_amdgcn_s_barrier();
  CFENCE;
  COMPUTE(2);  // t=14
  VMW(0);
  __builtin_amdgcn_s_barrier();
  CFENCE;
  COMPUTE(3);  // t=15

  // ---- epilogue: d -> (o0, o1) f32x2 store (stores never enter vmcnt window) ----
  const int rbase = m0 + wm * 64 + (lane >> 4) * 4;
  const bool full = (n0 + BN <= C_TOT);  // only n0=896 tile needs guarding

#pragma unroll
  for (int ni = 0; ni < 4; ++ni) {
    const int n = n0 + wn * 64 + ni * 16 + ar;   // < 1024 always
    if (full || n < C_TOT) {
      const float bd_r = bdiff[n];
#pragma unroll
      for (int mi = 0; mi < 4; ++mi) {
#pragma unroll
        for (int j = 0; j < 4; ++j) {
          const float d = acc[mi][ni][j] + bd_r;
          const float o0 = fminf(d, 0.0f) - __logf(1.0f + __expf(-fabsf(d)));
          const int row = rbase + mi * 16 + j;
          f32x2 v;
          v.x = o0;
          v.y = o0 - d;
          *(f32x2*)(out + (size_t)row * OUT_STRIDE + 2 * n) = v;
        }
      }
    }
  }
#undef STAGEAB
#undef COMPUTE
}

// ---------- naive fp32 fallback (only if ws too small) ----------
__global__ __launch_bounds__(256) void naive_kernel(const float* __restrict__ x,
                                                    const float* __restrict__ W,
                                                    const float* __restrict__ b,
                                                    float* __restrict__ out) {
  __shared__ float xs[K_TOT];
  const int row = blockIdx.x;
  for (int i = threadIdx.x; i < K_TOT; i += 256) xs[i] = x[(size_t)row * K_TOT + i];
  __syncthreads();
  for (int c = threadIdx.x; c < C_TOT; c += 256) {
    const float* w0 = W + (size_t)c * 1024;
    float l0 = b[c * 2], l1 = b[c * 2 + 1];
    for (int k = 0; k < K_TOT; ++k) {
      const float xv = xs[k];
      l0 += xv * w0[k];
      l1 += xv * w0[K_TOT + k];
    }
    const float d = l0 - l1;
    const float t = __logf(1.0f + __expf(-fabsf(d)));
    out[(size_t)row * OUT_STRIDE + c * 2]     = fminf(d, 0.0f) - t;
    out[(size_t)row * OUT_STRIDE + c * 2 + 1] = fminf(-d, 0.0f) - t;
  }
}

extern "C" void kernel_launch(void* const* d_in, const int* in_sizes, int n_in,
                              void* d_out, int out_size, void* d_ws, size_t ws_size,
                              hipStream_t stream) {
  const float* x = (const float*)d_in[0];   // [16384, 512]
  const float* W = (const float*)d_in[1];   // [1000, 2, 512]
  const float* b = (const float*)d_in[2];   // [1000, 2]
  float* out = (float*)d_out;               // [16384, 1000, 2]

  const size_t nx = (size_t)M_TOT * K_TOT;                  // 8388608 elems
  const size_t nwd = (size_t)N_PAD * K_TOT;                 // 524288 elems
  const size_t need = (nx + nwd) * sizeof(u16) + N_PAD * sizeof(float);

  if (ws_size < need) {
    naive_kernel<<<M_TOT, 256, 0, stream>>>(x, W, b, out);
    return;
  }

  u16* xb = (u16*)d_ws;
  u16* wd = xb + nx;
  float* bd = (float*)(wd + nwd);

  prep_kernel<<<4096 + 256, 256, 0, stream>>>(x, W, b, xb, wd, bd);
  gemm_ls_kernel<<<NWG, 256, 0, stream>>>(xb, wd, bd, out);
}

// Round 8
// 50.913 us; speedup vs baseline: 1.2022x; 1.0262x over previous
//
#include <hip/hip_runtime.h>
#include <cstdint>
#include <cstddef>

typedef unsigned short u16;
typedef unsigned int u32;
typedef __bf16 bf16x8 __attribute__((ext_vector_type(8)));
typedef float f32x4 __attribute__((ext_vector_type(4)));
typedef float f32x2 __attribute__((ext_vector_type(2)));
typedef u32 u32x4 __attribute__((ext_vector_type(4)));

#define M_TOT 16384
#define C_TOT 1000        // classes = GEMM N dimension
#define N_PAD 1024        // padded B rows
#define K_TOT 512
#define OUT_STRIDE 2000   // out row stride in floats
#define BM 128
#define BN 128
#define BK 32
#define NT 16             // K-tiles: 512/32
#define NWG 1024          // (16384/128) * (1024/128)

// ---------- f32 -> bf16 (RNE) ----------
__device__ __forceinline__ u16 f2bf(float f) {
  u32 u = __float_as_uint(f);
  u = (u + 0x7FFFu + ((u >> 16) & 1u)) >> 16;
  return (u16)u;
}

// packed RNE cvt: dst = bf16(lo) | bf16(hi)<<16
__device__ __forceinline__ u32 cvtpk(float lo, float hi) {
  u32 d;
  asm("v_cvt_pk_bf16_f32 %0, %1, %2" : "=v"(d) : "v"(lo), "v"(hi));
  return d;
}

// W prep: Wdiff[c,:] = bf16(W[c,0,:]-W[c,1,:]) zero-padded to 1024 rows; bdiff
__global__ __launch_bounds__(256) void wprep_kernel(const float* __restrict__ W,
                                                    const float* __restrict__ b,
                                                    u16* __restrict__ wd,
                                                    float* __restrict__ bd) {
  const int i = blockIdx.x * 256 + threadIdx.x;  // 65536 threads
  const int c = i >> 6;        // row 0..1023
  const int seg = i & 63;      // 8-elem segment of the 512-wide row
  ushort4 r0 = {0, 0, 0, 0}, r1 = {0, 0, 0, 0};
  if (c < C_TOT) {
    const float4* w0 = (const float4*)(W + (size_t)(2 * c) * K_TOT) + seg * 2;
    const float4* w1 = (const float4*)(W + (size_t)(2 * c + 1) * K_TOT) + seg * 2;
    float4 a0 = w0[0], a1 = w0[1], c0 = w1[0], c1 = w1[1];
    r0.x = f2bf(a0.x - c0.x); r0.y = f2bf(a0.y - c0.y);
    r0.z = f2bf(a0.z - c0.z); r0.w = f2bf(a0.w - c0.w);
    r1.x = f2bf(a1.x - c1.x); r1.y = f2bf(a1.y - c1.y);
    r1.z = f2bf(a1.z - c1.z); r1.w = f2bf(a1.w - c1.w);
    if (seg == 0) bd[c] = b[2 * c] - b[2 * c + 1];
  } else if (seg == 0) {
    bd[c] = 0.0f;
  }
  ushort4* d = (ushort4*)(wd + (size_t)c * K_TOT);
  d[seg * 2] = r0;
  d[seg * 2 + 1] = r1;
}

// ---------- async global -> LDS, 16B per lane ----------
__device__ __forceinline__ void gload_lds(const u16* g, u16* l) {
  __builtin_amdgcn_global_load_lds((const __attribute__((address_space(1))) u32*)g,
                                   (__attribute__((address_space(3))) u32*)l, 16, 0, 0);
}

// Stage one 8KB bf16 tile (128 rows x 32, stride K_TOT) into swizzled LDS.
// granule(r,q) -> lrow=r&63, pos=(((r>>6)<<2)|q)^(r&7), byte=lrow*128+pos*16.
__device__ __forceinline__ void stage8k(const u16* __restrict__ gbase,
                                        u16* lb, int tid) {
#pragma unroll
  for (int i = 0; i < 2; ++i) {
    const int g = i * 256 + tid;          // dest granule 0..511
    const int lrow = g >> 3;
    const int u = (g & 7) ^ (lrow & 7);   // inverse swizzle
    const int r = lrow | ((u >> 2) << 6);
    const int q = u & 3;
    gload_lds(gbase + (size_t)r * K_TOT + q * 8, lb + (size_t)g * 8);
  }
}

#define VMW(N) asm volatile("s_waitcnt vmcnt(" #N ")" ::: "memory")
#define CFENCE asm volatile("" ::: "memory")

// ---------- GEMM (M=16384, N=1024pad, K=512) + fused x-cvt + pairwise log_softmax ----------
// A: x f32 [M][512] -> reg-staged, cvt_pk to bf16, ds_write into swizzled LDS.
// B: Wdiff bf16 [1024][512] via global_load_lds (R7 path).
// 128x128 tile, 4 waves, acc[4][4]; 4 LDS buffers, depth-3 counted-vmcnt pipeline.
__global__ __launch_bounds__(256, 2) void gemm_ls_kernel(const float* __restrict__ Af,
                                                         const u16* __restrict__ B,
                                                         const float* __restrict__ bdiff,
                                                         float* __restrict__ out) {
  __shared__ u16 As[4][4096];  // 4 x 8KB
  __shared__ u16 Bs[4][4096];  // total 64KB static

  const int tid = threadIdx.x;
  const int lane = tid & 63;
  const int w = tid >> 6;
  const int wm = w >> 1;
  const int wn = w & 1;

  // XCD-chunked swizzle (NWG=1024, 128 blocks/XCD, bijective)
  const int bid = blockIdx.x;
  const int wg = (bid & 7) * (NWG / 8) + (bid >> 3);
  const int m0 = (wg >> 3) * BM;
  const int n0 = (wg & 7) * BN;

  const float* gAf = Af + (size_t)m0 * K_TOT;
  const u16* gB = B + (size_t)n0 * K_TOT;   // padded rows: unguarded

  // A staging source addresses (inverse-swizzled f32 granules for dest g=tid, 256+tid)
  const int lrow0 = tid >> 3;
  const int au = (tid & 7) ^ (lrow0 & 7);   // same u for both granules (256 ≡ 0 mod 8)
  const int qA = au & 3;
  const int rA0 = lrow0 | ((au >> 2) << 6);
  const int rA1 = (32 + lrow0) | ((au >> 2) << 6);
  const f32x4* gq0 = (const f32x4*)gAf + (size_t)rA0 * 128 + qA * 2;
  const f32x4* gq1 = (const f32x4*)gAf + (size_t)rA1 * 128 + qA * 2;

  // per-lane swizzled LDS byte offsets for the 4 A-frags / 4 B-frags
  const int ar = lane & 15;
  const int kq4 = lane >> 4;
  int offA[4], offB[4];
#pragma unroll
  for (int i = 0; i < 4; ++i) {
    int r = wm * 64 + i * 16 + ar;
    offA[i] = (r & 63) * 128 + (((((r >> 6) << 2) | kq4) ^ (r & 7)) << 4);
    r = wn * 64 + i * 16 + ar;
    offB[i] = (r & 63) * 128 + (((((r >> 6) << 2) | kq4) ^ (r & 7)) << 4);
  }

  f32x4 acc[4][4] = {};
  f32x4 areg[3][4];  // 3-deep A reg rotation, statically indexed (full unroll)

#define ALOAD(T)                                   \
  do {                                             \
    areg[(T) % 3][0] = gq0[(T) * 8];               \
    areg[(T) % 3][1] = gq0[(T) * 8 + 1];           \
    areg[(T) % 3][2] = gq1[(T) * 8];               \
    areg[(T) % 3][3] = gq1[(T) * 8 + 1];           \
  } while (0)

#define ACVT_WR(T)                                                        \
  do {                                                                    \
    u32x4 w0, w1;                                                         \
    w0.x = cvtpk(areg[(T) % 3][0].x, areg[(T) % 3][0].y);                 \
    w0.y = cvtpk(areg[(T) % 3][0].z, areg[(T) % 3][0].w);                 \
    w0.z = cvtpk(areg[(T) % 3][1].x, areg[(T) % 3][1].y);                 \
    w0.w = cvtpk(areg[(T) % 3][1].z, areg[(T) % 3][1].w);                 \
    w1.x = cvtpk(areg[(T) % 3][2].x, areg[(T) % 3][2].y);                 \
    w1.y = cvtpk(areg[(T) % 3][2].z, areg[(T) % 3][2].w);                 \
    w1.z = cvtpk(areg[(T) % 3][3].x, areg[(T) % 3][3].y);                 \
    w1.w = cvtpk(areg[(T) % 3][3].z, areg[(T) % 3][3].w);                 \
    *(u32x4*)(&As[(T) & 3][(size_t)tid * 8]) = w0;                        \
    *(u32x4*)(&As[(T) & 3][(size_t)(256 + tid) * 8]) = w1;                \
  } while (0)

#define BSTAGE(T) stage8k(gB + (T) * BK, &Bs[(T) & 3][0], tid)

#define COMPUTE(T)                                                          \
  do {                                                                      \
    bf16x8 af[4], bf[4];                                                    \
    _Pragma("unroll") for (int i = 0; i < 4; ++i)                           \
        af[i] = *(const bf16x8*)((const char*)&As[(T) & 3][0] + offA[i]);   \
    _Pragma("unroll") for (int i = 0; i < 4; ++i)                           \
        bf[i] = *(const bf16x8*)((const char*)&Bs[(T) & 3][0] + offB[i]);   \
    _Pragma("unroll") for (int mi = 0; mi < 4; ++mi)                        \
        _Pragma("unroll") for (int ni = 0; ni < 4; ++ni)                    \
            acc[mi][ni] = __builtin_amdgcn_mfma_f32_16x16x32_bf16(          \
                af[mi], bf[ni], acc[mi][ni], 0, 0, 0);                      \
  } while (0)

// per K-step: retire tile T (vmcnt), cvt+write A(T), prefetch A(T+3) to regs,
// publish LDS (lgkm+barrier), stage B(T+3), compute. 6 VMEM issued per step.
#define STEP(T, VMN)                                         \
  do {                                                       \
    VMW(VMN);                                                \
    CFENCE;                                                  \
    ACVT_WR(T);                                              \
    if ((T) + 3 < NT) ALOAD((T) + 3);                        \
    asm volatile("s_waitcnt lgkmcnt(0)" ::: "memory");       \
    __builtin_amdgcn_s_barrier();                            \
    CFENCE;                                                  \
    if ((T) + 3 < NT) BSTAGE((T) + 3);                       \
    __builtin_amdgcn_s_setprio(1);                           \
    COMPUTE(T);                                              \
    __builtin_amdgcn_s_setprio(0);                           \
  } while (0)

  // prologue: 3 tiles in flight (18 VMEM/thread: 4 A-loads + 2 B-gloads per tile)
  ALOAD(0); BSTAGE(0);
  ALOAD(1); BSTAGE(1);
  ALOAD(2); BSTAGE(2);

  STEP(0, 12);  STEP(1, 12);  STEP(2, 12);  STEP(3, 12);
  STEP(4, 12);  STEP(5, 12);  STEP(6, 12);  STEP(7, 12);
  STEP(8, 12);  STEP(9, 12);  STEP(10, 12); STEP(11, 12);
  STEP(12, 12); STEP(13, 12); STEP(14, 6);  STEP(15, 0);

  // ---- epilogue: d -> (o0, o1) f32x2 store ----
  const int rbase = m0 + wm * 64 + (lane >> 4) * 4;
  const bool full = (n0 + BN <= C_TOT);  // only n0=896 tile needs guarding

#pragma unroll
  for (int ni = 0; ni < 4; ++ni) {
    const int n = n0 + wn * 64 + ni * 16 + ar;   // < 1024 always
    if (full || n < C_TOT) {
      const float bd_r = bdiff[n];
#pragma unroll
      for (int mi = 0; mi < 4; ++mi) {
#pragma unroll
        for (int j = 0; j < 4; ++j) {
          const float d = acc[mi][ni][j] + bd_r;
          const float o0 = fminf(d, 0.0f) - __logf(1.0f + __expf(-fabsf(d)));
          const int row = rbase + mi * 16 + j;
          f32x2 v;
          v.x = o0;
          v.y = o0 - d;
          *(f32x2*)(out + (size_t)row * OUT_STRIDE + 2 * n) = v;
        }
      }
    }
  }
#undef ALOAD
#undef ACVT_WR
#undef BSTAGE
#undef COMPUTE
#undef STEP
}

// ---------- naive fp32 fallback (only if ws too small) ----------
__global__ __launch_bounds__(256) void naive_kernel(const float* __restrict__ x,
                                                    const float* __restrict__ W,
                                                    const float* __restrict__ b,
                                                    float* __restrict__ out) {
  __shared__ float xs[K_TOT];
  const int row = blockIdx.x;
  for (int i = threadIdx.x; i < K_TOT; i += 256) xs[i] = x[(size_t)row * K_TOT + i];
  __syncthreads();
  for (int c = threadIdx.x; c < C_TOT; c += 256) {
    const float* w0 = W + (size_t)c * 1024;
    float l0 = b[c * 2], l1 = b[c * 2 + 1];
    for (int k = 0; k < K_TOT; ++k) {
      const float xv = xs[k];
      l0 += xv * w0[k];
      l1 += xv * w0[K_TOT + k];
    }
    const float d = l0 - l1;
    const float t = __logf(1.0f + __expf(-fabsf(d)));
    out[(size_t)row * OUT_STRIDE + c * 2]     = fminf(d, 0.0f) - t;
    out[(size_t)row * OUT_STRIDE + c * 2 + 1] = fminf(-d, 0.0f) - t;
  }
}

extern "C" void kernel_launch(void* const* d_in, const int* in_sizes, int n_in,
                              void* d_out, int out_size, void* d_ws, size_t ws_size,
                              hipStream_t stream) {
  const float* x = (const float*)d_in[0];   // [16384, 512]
  const float* W = (const float*)d_in[1];   // [1000, 2, 512]
  const float* b = (const float*)d_in[2];   // [1000, 2]
  float* out = (float*)d_out;               // [16384, 1000, 2]

  const size_t nwd = (size_t)N_PAD * K_TOT;                 // 524288 elems
  const size_t need = nwd * sizeof(u16) + N_PAD * sizeof(float);

  if (ws_size < need) {
    naive_kernel<<<M_TOT, 256, 0, stream>>>(x, W, b, out);
    return;
  }

  u16* wd = (u16*)d_ws;
  float* bd = (float*)(wd + nwd);

  wprep_kernel<<<256, 256, 0, stream>>>(W, b, wd, bd);
  gemm_ls_kernel<<<NWG, 256, 0, stream>>>(x, wd, bd, out);
}

// Round 9
// 48.859 us; speedup vs baseline: 1.2528x; 1.0420x over previous
//
#include <hip/hip_runtime.h>
#include <cstdint>
#include <cstddef>

typedef unsigned short u16;
typedef unsigned int u32;
typedef __bf16 bf16x8 __attribute__((ext_vector_type(8)));
typedef float f32x4 __attribute__((ext_vector_type(4)));
typedef float f32x2 __attribute__((ext_vector_type(2)));
typedef u32 u32x4 __attribute__((ext_vector_type(4)));

#define M_TOT 16384
#define C_TOT 1000        // classes = GEMM N dimension
#define N_PAD 1024        // padded B rows
#define K_TOT 512
#define OUT_STRIDE 2000   // out row stride in floats
#define BM 128
#define BN 128
#define BK 32
#define NT 16             // K-tiles: 512/32
#define NWG 1024          // (16384/128) * (1024/128)

// ---------- f32 -> bf16 (RNE) ----------
__device__ __forceinline__ u16 f2bf(float f) {
  u32 u = __float_as_uint(f);
  u = (u + 0x7FFFu + ((u >> 16) & 1u)) >> 16;
  return (u16)u;
}

// packed RNE cvt: dst = bf16(lo) | bf16(hi)<<16
__device__ __forceinline__ u32 cvtpk(float lo, float hi) {
  u32 d;
  asm("v_cvt_pk_bf16_f32 %0, %1, %2" : "=v"(d) : "v"(lo), "v"(hi));
  return d;
}

// W prep: Wdiff[c,:] = bf16(W[c,0,:]-W[c,1,:]) zero-padded to 1024 rows; bdiff
__global__ __launch_bounds__(256) void wprep_kernel(const float* __restrict__ W,
                                                    const float* __restrict__ b,
                                                    u16* __restrict__ wd,
                                                    float* __restrict__ bd) {
  const int i = blockIdx.x * 256 + threadIdx.x;  // 65536 threads
  const int c = i >> 6;        // row 0..1023
  const int seg = i & 63;      // 8-elem segment of the 512-wide row
  ushort4 r0 = {0, 0, 0, 0}, r1 = {0, 0, 0, 0};
  if (c < C_TOT) {
    const float4* w0 = (const float4*)(W + (size_t)(2 * c) * K_TOT) + seg * 2;
    const float4* w1 = (const float4*)(W + (size_t)(2 * c + 1) * K_TOT) + seg * 2;
    float4 a0 = w0[0], a1 = w0[1], c0 = w1[0], c1 = w1[1];
    r0.x = f2bf(a0.x - c0.x); r0.y = f2bf(a0.y - c0.y);
    r0.z = f2bf(a0.z - c0.z); r0.w = f2bf(a0.w - c0.w);
    r1.x = f2bf(a1.x - c1.x); r1.y = f2bf(a1.y - c1.y);
    r1.z = f2bf(a1.z - c1.z); r1.w = f2bf(a1.w - c1.w);
    if (seg == 0) bd[c] = b[2 * c] - b[2 * c + 1];
  } else if (seg == 0) {
    bd[c] = 0.0f;
  }
  ushort4* d = (ushort4*)(wd + (size_t)c * K_TOT);
  d[seg * 2] = r0;
  d[seg * 2 + 1] = r1;
}

// ---------- async global -> LDS, 16B per lane ----------
__device__ __forceinline__ void gload_lds(const u16* g, u16* l) {
  __builtin_amdgcn_global_load_lds((const __attribute__((address_space(1))) u32*)g,
                                   (__attribute__((address_space(3))) u32*)l, 16, 0, 0);
}

// Stage one 8KB bf16 tile (128 rows x 32, stride K_TOT) into swizzled LDS.
// granule(r,q) -> lrow=r&63, pos=(((r>>6)<<2)|q)^(r&7), byte=lrow*128+pos*16.
__device__ __forceinline__ void stage8k(const u16* __restrict__ gbase,
                                        u16* lb, int tid) {
#pragma unroll
  for (int i = 0; i < 2; ++i) {
    const int g = i * 256 + tid;          // dest granule 0..511
    const int lrow = g >> 3;
    const int u = (g & 7) ^ (lrow & 7);   // inverse swizzle
    const int r = lrow | ((u >> 2) << 6);
    const int q = u & 3;
    gload_lds(gbase + (size_t)r * K_TOT + q * 8, lb + (size_t)g * 8);
  }
}

#define VMW(N) asm volatile("s_waitcnt vmcnt(" #N ")" ::: "memory")
#define CFENCE asm volatile("" ::: "memory")

// ---------- GEMM (M=16384, N=1024pad, K=512) + fused x-cvt + pairwise log_softmax ----------
// A: x f32 -> reg (depth-2) -> cvt_pk bf16 -> ds_write swizzled As[2] (published
//    in-step, 2 buffers suffice). B: Wdiff bf16 via gload_lds, Bs[3], depth-2.
// LDS 40KB -> 4 blocks/CU (16 waves/CU) to fix the measured latency-bound
// profile (MfmaUtil 8.6 / Occupancy 16.5 at 64KB, R8). vmcnt ledger: steady 2.
__global__ __launch_bounds__(256, 4) void gemm_ls_kernel(const float* __restrict__ Af,
                                                         const u16* __restrict__ B,
                                                         const float* __restrict__ bdiff,
                                                         float* __restrict__ out) {
  __shared__ u16 As[2][4096];  // 16 KB
  __shared__ u16 Bs[3][4096];  // 24 KB -> 40 KB total

  const int tid = threadIdx.x;
  const int lane = tid & 63;
  const int w = tid >> 6;
  const int wm = w >> 1;
  const int wn = w & 1;

  // XCD-chunked swizzle (NWG=1024, 128 blocks/XCD, bijective)
  const int bid = blockIdx.x;
  const int wg = (bid & 7) * (NWG / 8) + (bid >> 3);
  const int m0 = (wg >> 3) * BM;
  const int n0 = (wg & 7) * BN;

  const float* gAf = Af + (size_t)m0 * K_TOT;
  const u16* gB = B + (size_t)n0 * K_TOT;   // padded rows: unguarded

  // A staging source (inverse-swizzled f32 granules for dest g = tid, 256+tid)
  const int lrow0 = tid >> 3;
  const int au = (tid & 7) ^ (lrow0 & 7);
  const int qA = au & 3;
  const int rA0 = lrow0 | ((au >> 2) << 6);
  const int rA1 = (32 + lrow0) | ((au >> 2) << 6);
  const f32x4* gq0 = (const f32x4*)gAf + (size_t)rA0 * 128 + qA * 2;
  const f32x4* gq1 = (const f32x4*)gAf + (size_t)rA1 * 128 + qA * 2;

  // per-lane swizzled LDS byte offsets for the 4 A-frags / 4 B-frags
  const int ar = lane & 15;
  const int kq4 = lane >> 4;
  int offA[4], offB[4];
#pragma unroll
  for (int i = 0; i < 4; ++i) {
    int r = wm * 64 + i * 16 + ar;
    offA[i] = (r & 63) * 128 + (((((r >> 6) << 2) | kq4) ^ (r & 7)) << 4);
    r = wn * 64 + i * 16 + ar;
    offB[i] = (r & 63) * 128 + (((((r >> 6) << 2) | kq4) ^ (r & 7)) << 4);
  }

  f32x4 acc[4][4] = {};
  f32x4 areg[2][4];  // depth-2 A reg rotation, statically indexed (full unroll)

#define ALOAD(T)                                   \
  do {                                             \
    areg[(T) & 1][0] = gq0[(T) * 8];               \
    areg[(T) & 1][1] = gq0[(T) * 8 + 1];           \
    areg[(T) & 1][2] = gq1[(T) * 8];               \
    areg[(T) & 1][3] = gq1[(T) * 8 + 1];           \
  } while (0)

#define ACVT_WR(T)                                                        \
  do {                                                                    \
    u32x4 w0, w1;                                                         \
    w0.x = cvtpk(areg[(T) & 1][0].x, areg[(T) & 1][0].y);                 \
    w0.y = cvtpk(areg[(T) & 1][0].z, areg[(T) & 1][0].w);                 \
    w0.z = cvtpk(areg[(T) & 1][1].x, areg[(T) & 1][1].y);                 \
    w0.w = cvtpk(areg[(T) & 1][1].z, areg[(T) & 1][1].w);                 \
    w1.x = cvtpk(areg[(T) & 1][2].x, areg[(T) & 1][2].y);                 \
    w1.y = cvtpk(areg[(T) & 1][2].z, areg[(T) & 1][2].w);                 \
    w1.z = cvtpk(areg[(T) & 1][3].x, areg[(T) & 1][3].y);                 \
    w1.w = cvtpk(areg[(T) & 1][3].z, areg[(T) & 1][3].w);                 \
    *(u32x4*)(&As[(T) & 1][(size_t)tid * 8]) = w0;                        \
    *(u32x4*)(&As[(T) & 1][(size_t)(256 + tid) * 8]) = w1;                \
  } while (0)

#define BSTAGE(T) stage8k(gB + (T) * BK, &Bs[(T) % 3][0], tid)

#define COMPUTE(T)                                                          \
  do {                                                                      \
    bf16x8 af[4], bf[4];                                                    \
    _Pragma("unroll") for (int i = 0; i < 4; ++i)                           \
        af[i] = *(const bf16x8*)((const char*)&As[(T) & 1][0] + offA[i]);   \
    _Pragma("unroll") for (int i = 0; i < 4; ++i)                           \
        bf[i] = *(const bf16x8*)((const char*)&Bs[(T) % 3][0] + offB[i]);   \
    _Pragma("unroll") for (int mi = 0; mi < 4; ++mi)                        \
        _Pragma("unroll") for (int ni = 0; ni < 4; ++ni)                    \
            acc[mi][ni] = __builtin_amdgcn_mfma_f32_16x16x32_bf16(          \
                af[mi], bf[ni], acc[mi][ni], 0, 0, 0);                      \
  } while (0)

// per K-step. vmcnt ledger (sim'd): prologue A0|B0|B1 = 8 outstanding;
// steady: wait(2) retires {A(T),B(T)}; issue A(T+1) [4] + B(T+2) [2].
#define STEP(T, VMN)                                         \
  do {                                                       \
    VMW(VMN);                                                \
    CFENCE;                                                  \
    ACVT_WR(T);                                              \
    if ((T) + 1 < NT) ALOAD((T) + 1);                        \
    asm volatile("s_waitcnt lgkmcnt(0)" ::: "memory");       \
    __builtin_amdgcn_s_barrier();                            \
    CFENCE;                                                  \
    if ((T) + 2 < NT) BSTAGE((T) + 2);                       \
    __builtin_amdgcn_s_setprio(1);                           \
    COMPUTE(T);                                              \
    __builtin_amdgcn_s_setprio(0);                           \
  } while (0)

  // prologue: A0 regs, B0/B1 LDS in flight (issue order matters for vmcnt)
  ALOAD(0);
  CFENCE;
  BSTAGE(0);
  BSTAGE(1);
  CFENCE;

  STEP(0, 2);   STEP(1, 2);   STEP(2, 2);   STEP(3, 2);
  STEP(4, 2);   STEP(5, 2);   STEP(6, 2);   STEP(7, 2);
  STEP(8, 2);   STEP(9, 2);   STEP(10, 2);  STEP(11, 2);
  STEP(12, 2);  STEP(13, 2);  STEP(14, 2);  STEP(15, 0);

  // ---- epilogue: d -> (o0, o1) f32x2 store ----
  const int rbase = m0 + wm * 64 + (lane >> 4) * 4;
  const bool full = (n0 + BN <= C_TOT);  // only n0=896 tile needs guarding

#pragma unroll
  for (int ni = 0; ni < 4; ++ni) {
    const int n = n0 + wn * 64 + ni * 16 + ar;   // < 1024 always
    if (full || n < C_TOT) {
      const float bd_r = bdiff[n];
#pragma unroll
      for (int mi = 0; mi < 4; ++mi) {
#pragma unroll
        for (int j = 0; j < 4; ++j) {
          const float d = acc[mi][ni][j] + bd_r;
          const float o0 = fminf(d, 0.0f) - __logf(1.0f + __expf(-fabsf(d)));
          const int row = rbase + mi * 16 + j;
          f32x2 v;
          v.x = o0;
          v.y = o0 - d;
          *(f32x2*)(out + (size_t)row * OUT_STRIDE + 2 * n) = v;
        }
      }
    }
  }
#undef ALOAD
#undef ACVT_WR
#undef BSTAGE
#undef COMPUTE
#undef STEP
}

// ---------- naive fp32 fallback (only if ws too small) ----------
__global__ __launch_bounds__(256) void naive_kernel(const float* __restrict__ x,
                                                    const float* __restrict__ W,
                                                    const float* __restrict__ b,
                                                    float* __restrict__ out) {
  __shared__ float xs[K_TOT];
  const int row = blockIdx.x;
  for (int i = threadIdx.x; i < K_TOT; i += 256) xs[i] = x[(size_t)row * K_TOT + i];
  __syncthreads();
  for (int c = threadIdx.x; c < C_TOT; c += 256) {
    const float* w0 = W + (size_t)c * 1024;
    float l0 = b[c * 2], l1 = b[c * 2 + 1];
    for (int k = 0; k < K_TOT; ++k) {
      const float xv = xs[k];
      l0 += xv * w0[k];
      l1 += xv * w0[K_TOT + k];
    }
    const float d = l0 - l1;
    const float t = __logf(1.0f + __expf(-fabsf(d)));
    out[(size_t)row * OUT_STRIDE + c * 2]     = fminf(d, 0.0f) - t;
    out[(size_t)row * OUT_STRIDE + c * 2 + 1] = fminf(-d, 0.0f) - t;
  }
}

extern "C" void kernel_launch(void* const* d_in, const int* in_sizes, int n_in,
                              void* d_out, int out_size, void* d_ws, size_t ws_size,
                              hipStream_t stream) {
  const float* x = (const float*)d_in[0];   // [16384, 512]
  const float* W = (const float*)d_in[1];   // [1000, 2, 512]
  const float* b = (const float*)d_in[2];   // [1000, 2]
  float* out = (float*)d_out;               // [16384, 1000, 2]

  const size_t nwd = (size_t)N_PAD * K_TOT;                 // 524288 elems
  const size_t need = nwd * sizeof(u16) + N_PAD * sizeof(float);

  if (ws_size < need) {
    naive_kernel<<<M_TOT, 256, 0, stream>>>(x, W, b, out);
    return;
  }

  u16* wd = (u16*)d_ws;
  float* bd = (float*)(wd + nwd);

  wprep_kernel<<<256, 256, 0, stream>>>(W, b, wd, bd);
  gemm_ls_kernel<<<NWG, 256, 0, stream>>>(x, wd, bd, out);
}